// Round 17
// baseline (240.712 us; speedup 1.0000x reference)
//
#include <hip/hip_runtime.h>

#define NIN 784
#define H0 256
#define H1 128
#define H2 64
#define H3 32
#define NOUT 10
#define BATCH 128
#define TT 500
#define KCH0 25
#define JTILES 16

// d_out offsets (floats)
#define H1_OFF (BATCH * H0 * TT)
#define H2_OFF (H1_OFF + BATCH * H1 * TT)
#define H3_OFF (H2_OFF + BATCH * H2 * TT)
#define OUT_OFF (H3_OFF + BATCH * H3 * TT)
#define RATE_OFF (OUT_OFF + BATCH * NOUT * TT)

typedef __attribute__((ext_vector_type(8))) short short8v;
typedef __attribute__((ext_vector_type(4))) float f32x4;

__device__ __forceinline__ unsigned short f2bf(float f) {
  union { float f; unsigned u; } v; v.f = f;
  unsigned r = v.u + 0x7FFFu + ((v.u >> 16) & 1u);  // RNE
  return (unsigned short)(r >> 16);
}
__device__ __forceinline__ float bf2f(unsigned short b) {
  union { unsigned u; float f; } v; v.u = ((unsigned)b) << 16;
  return v.f;
}

// LIF step, shortened dependent chain: E=e^{-x}, s=1/(1+E), v*(1-s)=v*E/(1+E).
__device__ __forceinline__ float lif_step(float& v, float c) {
  v = 0.5f * (v + c);
  const float E = __expf(5.0f * (1.0f - v));
  const float r = 1.0f / (1.0f + E);
  v = v * E * r;
  return r;  // = s
}

// ---------------- pack_all: w0 -> A-frags, w1..w4 -> B-frags (verified) -------
__global__ void pack_all(const float* __restrict__ w0, const float* __restrict__ w1,
                         const float* __restrict__ w2, const float* __restrict__ w3,
                         const float* __restrict__ w4, unsigned short* __restrict__ Wf,
                         unsigned short* __restrict__ Bf) {
  const int bid = blockIdx.x, l = threadIdx.x;
  if (bid < JTILES * KCH0) {
    const int jt = bid / KCH0, kc = bid % KCH0;
    const int j = jt * 16 + (l & 15);
    const int kbase = kc * 32 + (l >> 4) * 8;
    unsigned v[4];
#pragma unroll
    for (int e = 0; e < 4; ++e) {
      const int k0 = kbase + e * 2;
      const float f0 = (k0 < NIN) ? fmaxf(w0[(size_t)k0 * H0 + j], 0.0f) : 0.0f;
      const float f1 = (k0 + 1 < NIN) ? fmaxf(w0[(size_t)(k0 + 1) * H0 + j], 0.0f) : 0.0f;
      v[e] = (unsigned)f2bf(f0) | ((unsigned)f2bf(f1) << 16);
    }
    uint4 o; o.x = v[0]; o.y = v[1]; o.z = v[2]; o.w = v[3];
    reinterpret_cast<uint4*>(Wf)[(size_t)bid * 64 + l] = o;
    return;
  }
  const int tile = bid - JTILES * KCH0;
  const float* w; int K, Nw, base, rel, KCH;
  if (tile < 64)      { w = w1; K = 256; Nw = 128; base = 0;        rel = tile;      KCH = 8; }
  else if (tile < 80) { w = w2; K = 128; Nw = 64;  base = 64 * 512; rel = tile - 64; KCH = 4; }
  else if (tile < 84) { w = w3; K = 64;  Nw = 32;  base = 80 * 512; rel = tile - 80; KCH = 2; }
  else                { w = w4; K = 32;  Nw = 10;  base = 84 * 512; rel = 0;         KCH = 1; }
  const int nt = rel / KCH, kc = rel % KCH;
  const int n = nt * 16 + (l & 15);
  const int kb = kc * 32 + (l >> 4) * 8;
  unsigned v[4];
#pragma unroll
  for (int e = 0; e < 4; ++e) {
    const int k0 = kb + e * 2;
    const float f0 = (n < Nw && k0 < K)     ? fmaxf(w[(size_t)k0 * Nw + n], 0.0f) : 0.0f;
    const float f1 = (n < Nw && k0 + 1 < K) ? fmaxf(w[(size_t)(k0 + 1) * Nw + n], 0.0f) : 0.0f;
    v[e] = (unsigned)f2bf(f0) | ((unsigned)f2bf(f1) << 16);
  }
  uint4 o; o.x = v[0]; o.y = v[1]; o.z = v[2]; o.w = v[3];
  *reinterpret_cast<uint4*>(Bf + base + ((size_t)rel * 64 + l) * 8) = o;
}

// ---------------- gemm0: float4-staged X, 1-deep prefetch (verified r13/r15) --
__global__ __launch_bounds__(256, 4) void gemm0(
    const float* __restrict__ X, const unsigned short* __restrict__ Wf,
    unsigned short* __restrict__ cur0) {
  const int ttile = blockIdx.x;
  const int b = blockIdx.y;
  const int tid = threadIdx.x;
  const int wave = tid >> 6, lane = tid & 63;
  const int t0 = ttile * 64;
  __shared__ unsigned short Xs[2][64 * 40];
  f32x4 acc[4][4];
#pragma unroll
  for (int i = 0; i < 4; ++i)
#pragma unroll
    for (int jj = 0; jj < 4; ++jj) acc[i][jj] = (f32x4)0.0f;

  const float* Xb = X + (size_t)b * NIN * TT;
  const int kq = tid >> 4;
  const int tf4 = tid & 15;
  const int lrow = lane & 15, lgrp = lane >> 4;
  const bool t4in = (t0 + tf4 * 4) < TT;

  float4 rA[2];
#define LOADX4(R, KC)                                                           \
  do {                                                                          \
    _Pragma("unroll") for (int p = 0; p < 2; ++p) {                             \
      const int k_ = (KC) * 32 + kq + p * 16;                                   \
      if (t4in && k_ < NIN)                                                     \
        (R)[p] = *reinterpret_cast<const float4*>(Xb + (size_t)k_ * TT + t0 + tf4 * 4); \
      else                                                                      \
        (R)[p] = make_float4(0.f, 0.f, 0.f, 0.f);                               \
    }                                                                           \
  } while (0)

  LOADX4(rA, 0);

  for (int kc = 0; kc < KCH0; ++kc) {
    unsigned short* xbuf = Xs[kc & 1];
#pragma unroll
    for (int p = 0; p < 2; ++p) {
      const float* f = reinterpret_cast<const float*>(&rA[p]);
#pragma unroll
      for (int i = 0; i < 4; ++i)
        xbuf[(tf4 * 4 + i) * 40 + kq + p * 16] = f2bf(f[i]);
    }
    __syncthreads();
    if (kc + 1 < KCH0) LOADX4(rA, kc + 1);
    short8v afr[4], bfr[4];
#pragma unroll
    for (int jf = 0; jf < 4; ++jf) {
      const size_t off = ((size_t)((wave * 4 + jf) * KCH0 + kc) * 64 + lane) * 8;
      afr[jf] = *reinterpret_cast<const short8v*>(Wf + off);
    }
#pragma unroll
    for (int tf = 0; tf < 4; ++tf)
      bfr[tf] = *reinterpret_cast<const short8v*>(&xbuf[(tf * 16 + lrow) * 40 + lgrp * 8]);
#pragma unroll
    for (int jf = 0; jf < 4; ++jf)
#pragma unroll
      for (int tf = 0; tf < 4; ++tf)
        acc[jf][tf] = __builtin_amdgcn_mfma_f32_16x16x32_bf16(afr[jf], bfr[tf], acc[jf][tf], 0, 0, 0);
  }
#undef LOADX4

#pragma unroll
  for (int tf = 0; tf < 4; ++tf) {
    const int t = t0 + tf * 16 + lrow;
    if (t >= TT) continue;
    unsigned short* row = cur0 + ((size_t)b * TT + t) * H0;
#pragma unroll
    for (int jf = 0; jf < 4; ++jf) {
      const int j = wave * 64 + jf * 16 + lgrp * 4;
      const f32x4 a = acc[jf][tf];
      const unsigned p0 = (unsigned)f2bf(a[0]) | ((unsigned)f2bf(a[1]) << 16);
      const unsigned p1 = (unsigned)f2bf(a[2]) | ((unsigned)f2bf(a[3]) << 16);
      *reinterpret_cast<unsigned*>(row + j) = p0;
      *reinterpret_cast<unsigned*>(row + j + 2) = p1;
    }
  }
}

// ---------------- scan_par: t-parallel LIF scan with 32-step warm-up ----------
// v decays by >=0.5x per step, so starting a chunk from v=0 at t0-32 and
// discarding 32 warm-up steps reproduces the exact state to ~2^-32 (<< bf16
// quantization). 8 chunks/neuron -> 8x parallelism; no serial bottleneck.
// cur: [b][RS][H] bf16, row r = step t=r. s (if WRITE_S): [b][512][H], slot t+1.
template<int H, int RS, int HACT, bool WRITE_S>
__global__ __launch_bounds__(64) void scan_par(
    const unsigned short* __restrict__ cur, unsigned short* __restrict__ s,
    float* __restrict__ h) {
  const int c = blockIdx.x, jg = blockIdx.y, b = blockIdx.z;
  const int l = threadIdx.x;
  const int j = jg * 64 + l;
  if (j >= HACT) return;
  const unsigned short* cp = cur + (size_t)b * RS * H + j;
  float* hp = h + ((size_t)b * HACT + j) * TT;
  unsigned short* sp = WRITE_S ? (s + (size_t)b * 512 * H + j) : nullptr;
  float v = 0.0f;
  const int t0 = c * 64;
  float c0[16], c1[16];
#define LD16(D, T) _Pragma("unroll") for (int u = 0; u < 16; ++u) (D)[u] = bf2f(cp[(size_t)((T) + u) * H]);
#define PR16(C, T)                                                        \
  do {                                                                    \
    float hb[16];                                                         \
    _Pragma("unroll")                                                     \
    for (int u = 0; u < 16; ++u) {                                        \
      const float sv = lif_step(v, (C)[u]);                               \
      hb[u] = sv;                                                         \
      if (WRITE_S) sp[(size_t)((T) + u + 1) * H] = f2bf(sv);              \
    }                                                                     \
    _Pragma("unroll")                                                     \
    for (int q = 0; q < 4; ++q)                                           \
      *reinterpret_cast<float4*>(hp + (T) + q * 4) =                      \
          make_float4(hb[q * 4], hb[q * 4 + 1], hb[q * 4 + 2], hb[q * 4 + 3]); \
  } while (0)
  if (c > 0) {  // warm-up t0-32 .. t0-1, outputs discarded
    LD16(c0, t0 - 32);
    LD16(c1, t0 - 16);
#pragma unroll
    for (int u = 0; u < 16; ++u) lif_step(v, c0[u]);
#pragma unroll
    for (int u = 0; u < 16; ++u) lif_step(v, c1[u]);
  } else if (WRITE_S) {
    sp[0] = 0;
  }
  LD16(c0, t0);
  if (c < 7) {  // 64 steps
    LD16(c1, t0 + 16);
    PR16(c0, t0);
    LD16(c0, t0 + 32);
    PR16(c1, t0 + 16);
    LD16(c1, t0 + 48);
    PR16(c0, t0 + 32);
    PR16(c1, t0 + 48);
  } else {  // steps 448..499 (52)
    LD16(c1, 464);
    PR16(c0, 448);
    LD16(c0, 480);
    PR16(c1, 464);
#pragma unroll
    for (int u = 0; u < 4; ++u) c1[u] = bf2f(cp[(size_t)(496 + u) * H]);
    PR16(c0, 480);
    {
      float hb[4];
#pragma unroll
      for (int u = 0; u < 4; ++u) {
        const float sv = lif_step(v, c1[u]);
        hb[u] = sv;
        if (WRITE_S) sp[(size_t)(497 + u) * H] = f2bf(sv);
      }
      *reinterpret_cast<float4*>(hp + 496) = make_float4(hb[0], hb[1], hb[2], hb[3]);
    }
  }
#undef LD16
#undef PR16
}

// ---------------- gemm_l: C[b][r][n] = S[b][r][:] @ Bfrag (full machine) ------
// Row r = step t=r (uses spike slot r = s_{t-1}). B-frags staged in LDS once.
template<int K, int N, int NT, int KCH>
__global__ __launch_bounds__(256) void gemm_l(
    const unsigned short* __restrict__ S, const unsigned short* __restrict__ Bf,
    unsigned short* __restrict__ C) {
  __shared__ __align__(16) unsigned short wl[NT * KCH * 512];
  const int b = blockIdx.y, tid = threadIdx.x;
  const int w = tid >> 6, lane = tid & 63, lr = lane & 15, lg = lane >> 4;
  {
    const uint4* src = reinterpret_cast<const uint4*>(Bf);
    uint4* dst = reinterpret_cast<uint4*>(wl);
    for (int i = tid; i < NT * KCH * 512 / 8; i += 256) dst[i] = src[i];
  }
  const int t0 = blockIdx.x * 64 + w * 16;
  const unsigned short* ap = S + ((size_t)b * 512 + t0 + lr) * K + lg * 8;
  short8v a[KCH];
#pragma unroll
  for (int kc = 0; kc < KCH; ++kc) a[kc] = *reinterpret_cast<const short8v*>(ap + kc * 32);
  __syncthreads();
  unsigned short* cb = C + ((size_t)b * 512 + t0 + lg * 4) * N + lr;
#pragma unroll
  for (int nt = 0; nt < NT; ++nt) {
    f32x4 acc = (f32x4)0.0f;
#pragma unroll
    for (int kc = 0; kc < KCH; ++kc) {
      const short8v bf = *reinterpret_cast<const short8v*>(wl + ((size_t)(nt * KCH + kc) * 64 + lane) * 8);
      acc = __builtin_amdgcn_mfma_f32_16x16x32_bf16(a[kc], bf, acc, 0, 0, 0);
    }
#pragma unroll
    for (int r = 0; r < 4; ++r) cb[(size_t)r * N + nt * 16] = f2bf(acc[r]);
  }
}

// ---------------- rates: mean over t of stored output spikes ------------------
__global__ __launch_bounds__(64) void rates_k(const float* __restrict__ oo,
                                              float* __restrict__ rates) {
  const int idx = blockIdx.x * 64 + threadIdx.x;
  if (idx >= BATCH * NOUT) return;
  const float* p = oo + (size_t)idx * TT;
  float acc = 0.0f;
  for (int t = 0; t < TT; t += 4) {
    const float4 v = *reinterpret_cast<const float4*>(p + t);
    acc += v.x + v.y + v.z + v.w;
  }
  rates[idx] = acc * (1.0f / (float)TT);
}

extern "C" void kernel_launch(void* const* d_in, const int* in_sizes, int n_in,
                              void* d_out, int out_size, void* d_ws, size_t ws_size,
                              hipStream_t stream) {
  const float* X  = (const float*)d_in[0];
  const float* w0 = (const float*)d_in[1];
  const float* w1 = (const float*)d_in[2];
  const float* w2 = (const float*)d_in[3];
  const float* w3 = (const float*)d_in[4];
  const float* w4 = (const float*)d_in[5];
  float* out = (float*)d_out;

  uint8_t* ws = (uint8_t*)d_ws;
  const size_t SLOT = 33554432;
  // slotA: cur0 -> cur1 -> cur2 -> cur3 -> cur4 (each consumed before overwrite)
  // slotB: s0 -> s1 -> s2 -> s3
  unsigned short* slotA = (unsigned short*)ws;
  unsigned short* slotB = (unsigned short*)(ws + SLOT);
  unsigned short* Wf0   = (unsigned short*)(ws + 2 * SLOT);
  unsigned short* Bf2   = Wf0 + (size_t)JTILES * KCH0 * 64 * 8;

  unsigned short* cur0 = slotA;  // [b][500][256]
  unsigned short* s0   = slotB;  // [b][512][256]
  unsigned short* cur1 = slotA;  // [b][512][128]
  unsigned short* s1   = slotB;  // [b][512][128]
  unsigned short* cur2 = slotA;  // [b][512][64]
  unsigned short* s2   = slotB;  // [b][512][64]
  unsigned short* cur3 = slotA;  // [b][512][32]
  unsigned short* s3   = slotB;  // [b][512][32]
  unsigned short* cur4 = slotA;  // [b][512][16]

  pack_all<<<JTILES * KCH0 + 85, 64, 0, stream>>>(w0, w1, w2, w3, w4, Wf0, Bf2);
  gemm0<<<dim3(8, BATCH), 256, 0, stream>>>(X, Wf0, cur0);

  scan_par<256, 500, 256, true><<<dim3(8, 4, BATCH), 64, 0, stream>>>(cur0, s0, out);
  gemm_l<256, 128, 8, 8><<<dim3(8, BATCH), 256, 0, stream>>>(s0, Bf2, cur1);

  scan_par<128, 512, 128, true><<<dim3(8, 2, BATCH), 64, 0, stream>>>(cur1, s1, out + H1_OFF);
  gemm_l<128, 64, 4, 4><<<dim3(8, BATCH), 256, 0, stream>>>(s1, Bf2 + 64 * 512, cur2);

  scan_par<64, 512, 64, true><<<dim3(8, 1, BATCH), 64, 0, stream>>>(cur2, s2, out + H2_OFF);
  gemm_l<64, 32, 2, 2><<<dim3(8, BATCH), 256, 0, stream>>>(s2, Bf2 + 80 * 512, cur3);

  scan_par<32, 512, 32, true><<<dim3(8, 1, BATCH), 64, 0, stream>>>(cur3, s3, out + H3_OFF);
  gemm_l<32, 16, 1, 1><<<dim3(8, BATCH), 256, 0, stream>>>(s3, Bf2 + 84 * 512, cur4);

  scan_par<16, 512, 10, false><<<dim3(8, 1, BATCH), 64, 0, stream>>>(cur4, nullptr, out + OUT_OFF);
  rates_k<<<(BATCH * NOUT + 63) / 64, 64, 0, stream>>>(out + OUT_OFF, out + RATE_OFF);
}